// Round 1
// baseline (118.516 us; speedup 1.0000x reference)
//
#include <hip/hip_runtime.h>
#include <math.h>

#define NB 8
#define NQ 512
#define NK 512
#define NH 64
#define ND 256

#define QT 8     // q rows per block
#define KT 64    // k cols per tile

#if __has_builtin(__builtin_amdgcn_exp2f)
#define EXP2(x) __builtin_amdgcn_exp2f(x)
#else
#define EXP2(x) exp2f(x)
#endif
#if __has_builtin(__builtin_amdgcn_rcpf)
#define RCP(x) __builtin_amdgcn_rcpf(x)
#else
#define RCP(x) (1.0f / (x))
#endif

// ---------------- projection: qp = (query @ Wq) * 2log2e, kp = (key @ Wk) * 2log2e
// grid 512: blocks [0,256) -> query rows, [256,512) -> key rows. 16 rows/block.
__global__ __launch_bounds__(256) void proj_kernel(
    const float* __restrict__ query, const float* __restrict__ key,
    const float* __restrict__ Wq, const float* __restrict__ Wk,
    float* __restrict__ qp, float* __restrict__ kp)
{
    __shared__ float Ws[ND * NH];  // 64 KB
    const bool isK = blockIdx.x >= 256;
    const float* __restrict__ in = isK ? key : query;
    const float* __restrict__ W  = isK ? Wk : Wq;
    float* __restrict__ outp     = isK ? kp : qp;
    const int rowbase = (blockIdx.x & 255) * 16;

    for (int i = threadIdx.x * 4; i < ND * NH; i += 256 * 4)
        *(float4*)&Ws[i] = *(const float4*)&W[i];
    __syncthreads();

    const int h = threadIdx.x & 63;
    const int w = threadIdx.x >> 6;
    for (int rr = 0; rr < 4; ++rr) {
        const int row = rowbase + w * 4 + rr;
        const float* __restrict__ inr = in + row * ND;
        float acc = 0.f;
        #pragma unroll 8
        for (int d = 0; d < ND; ++d)
            acc = fmaf(inr[d], Ws[d * NH + h], acc);
        outp[row * NH + h] = acc * 2.8853900817779268f;  // 2*log2(e)
    }
}

// ---------------- fused score + softmax + PV
// grid = NB * (NQ/QT) = 512 blocks, 256 threads (4 waves).
__global__ __launch_bounds__(256) void attn_kernel(
    const float* __restrict__ qp, const float* __restrict__ kp,
    const float* __restrict__ value, const unsigned char* __restrict__ mask,
    const float* __restrict__ w_v, float* __restrict__ out)
{
    __shared__ float qs[QT * NH];        // 2 KB   (pre-scaled q-proj)
    __shared__ float kt[NH][KT + 1];     // 16.25 KB (transposed k-proj tile, padded)
    __shared__ float sc[QT][NK];         // 16 KB  (scores -> probs)
    __shared__ float wv2[NH];
    __shared__ float rinv[QT];

    const int b    = blockIdx.x >> 6;          // NQ/QT = 64 tiles per batch
    const int q0   = (blockIdx.x & 63) * QT;
    const int t    = threadIdx.x;
    const int lane = t & 63;
    const int wid  = t >> 6;                   // wave id 0..3

    for (int i = t; i < QT * NH; i += 256)
        qs[i] = qp[(b * NQ + q0) * NH + i];
    if (t < NH) wv2[t] = 2.0f * w_v[t];
    __syncthreads();

    // wsum = sum_h w_v[h]  (broadcast LDS reads, one-time)
    float wsum = 0.f;
    #pragma unroll
    for (int hh = 0; hh < NH; ++hh) wsum += wv2[hh];
    wsum *= 0.5f;

    // ---- score phase: score = wsum - sum_h (2 w_h) * rcp(1 + exp2(q'+k'))
    const int kr = lane;
    const int qg = wid;          // thread handles rows qg and qg+4
    for (int k0 = 0; k0 < NK; k0 += KT) {
        __syncthreads();         // protect kt against readers of previous tile
        for (int r = wid; r < KT; r += 4)
            kt[lane][r] = kp[(b * NK + k0 + r) * NH + lane];
        __syncthreads();

        float a0 = 0.f, a1 = 0.f;
        #pragma unroll
        for (int h = 0; h < NH; ++h) {
            const float kh = kt[h][kr];
            const float w2 = wv2[h];
            const float t0 = EXP2(qs[qg * NH + h] + kh);
            const float t1 = EXP2(qs[(qg + 4) * NH + h] + kh);
            a0 = fmaf(w2, RCP(1.0f + t0), a0);
            a1 = fmaf(w2, RCP(1.0f + t1), a1);
        }
        const int k = k0 + kr;
        const unsigned char m0 = mask[(b * NQ + q0 + qg) * NK + k];
        const unsigned char m1 = mask[(b * NQ + q0 + qg + 4) * NK + k];
        sc[qg][k]     = m0 ? -__builtin_inff() : (wsum - a0);
        sc[qg + 4][k] = m1 ? -__builtin_inff() : (wsum - a1);
    }
    __syncthreads();

    // ---- softmax: each wave handles 2 rows; lane owns 8 elements
    for (int row = wid; row < QT; row += 4) {
        float vals[8];
        float m = -__builtin_inff();
        #pragma unroll
        for (int j = 0; j < 8; ++j) {
            vals[j] = sc[row][lane + 64 * j];
            m = fmaxf(m, vals[j]);
        }
        #pragma unroll
        for (int off = 32; off > 0; off >>= 1)
            m = fmaxf(m, __shfl_xor(m, off, 64));
        float s = 0.f;
        #pragma unroll
        for (int j = 0; j < 8; ++j) {
            const float p = EXP2((vals[j] - m) * 1.4426950408889634f);
            sc[row][lane + 64 * j] = p;
            s += p;
        }
        #pragma unroll
        for (int off = 32; off > 0; off >>= 1)
            s += __shfl_xor(s, off, 64);
        if (lane == 0) rinv[row] = 1.0f / s;
    }
    __syncthreads();

    // ---- PV: wave owns 64 d-columns; denominator folded into epilogue
    const int d = wid * 64 + lane;
    float acc[QT];
    #pragma unroll
    for (int i = 0; i < QT; ++i) acc[i] = 0.f;
    for (int k = 0; k < NK; k += 4) {
        #pragma unroll
        for (int kk = 0; kk < 4; ++kk) {
            const float v = value[(b * NK + k + kk) * ND + d];
            #pragma unroll
            for (int i = 0; i < QT; ++i)
                acc[i] = fmaf(sc[i][k + kk], v, acc[i]);
        }
    }
    #pragma unroll
    for (int i = 0; i < QT; ++i)
        out[(b * NQ + q0 + i) * ND + d] = acc[i] * rinv[i];
}

extern "C" void kernel_launch(void* const* d_in, const int* in_sizes, int n_in,
                              void* d_out, int out_size, void* d_ws, size_t ws_size,
                              hipStream_t stream) {
    const float* key   = (const float*)d_in[0];
    const float* query = (const float*)d_in[1];
    const float* value = (const float*)d_in[2];
    const unsigned char* mask = (const unsigned char*)d_in[3];
    const float* Wk  = (const float*)d_in[4];
    const float* Wq  = (const float*)d_in[5];
    const float* w_v = (const float*)d_in[6];
    float* out = (float*)d_out;

    float* qp = (float*)d_ws;              // [NB*NQ, NH]
    float* kp = qp + NB * NQ * NH;         // [NB*NK, NH]

    proj_kernel<<<512, 256, 0, stream>>>(query, key, Wq, Wk, qp, kp);
    attn_kernel<<<NB * (NQ / QT), 256, 0, stream>>>(qp, kp, value, mask, w_v, out);
}

// Round 2
// 70.696 us; speedup vs baseline: 1.6764x; 1.6764x over previous
//
#include <hip/hip_runtime.h>
#include <math.h>

#define NB 8
#define NQ 512
#define NK 512
#define NH 64
#define ND 256
#define QT 8     // q rows per attn block (= waves per block)
#define KT 64    // k cols per tile

typedef float f32x2 __attribute__((ext_vector_type(2)));
typedef float f32x4 __attribute__((ext_vector_type(4)));

#if __has_builtin(__builtin_amdgcn_exp2f)
#define EXP2(x) __builtin_amdgcn_exp2f(x)
#else
#define EXP2(x) exp2f(x)
#endif
#if __has_builtin(__builtin_amdgcn_rcpf)
#define RCP(x) __builtin_amdgcn_rcpf(x)
#else
#define RCP(x) (1.0f / (x))
#endif

#define SCALE2 2.8853900817779268f   // 2*log2(e) folded into projections
#define LOG2E  1.4426950408889634f

// ---------------- projection: qp = (query @ Wq) * 2log2e, kp = (key @ Wk) * 2log2e
// 512 blocks x 512 threads; 16 rows/block; blocks >=256 handle key rows.
// Input rows staged in LDS; W read via wave-uniform scalar loads (s_load).
__global__ __launch_bounds__(512, 4) void proj_kernel(
    const float* __restrict__ query, const float* __restrict__ key,
    const float* __restrict__ Wq, const float* __restrict__ Wk,
    float* __restrict__ qp, float* __restrict__ kp)
{
    __shared__ float ins[16][ND + 4];
    const int t = threadIdx.x;
    const bool isK = blockIdx.x >= 256;
    const float* __restrict__ in = isK ? key : query;
    const float* __restrict__ W  = isK ? Wk : Wq;
    float* __restrict__ outp     = isK ? kp : qp;
    const int rowbase = (blockIdx.x & 255) * 16;

    {   // stage 16 rows x 256 floats, coalesced
        const int r = t >> 5;            // 0..15
        const int c = (t & 31) * 8;      // 0..248
        const float* src = in + (size_t)(rowbase + r) * ND + c;
        f32x4 v0 = *(const f32x4*)(src);
        f32x4 v1 = *(const f32x4*)(src + 4);
        *(f32x4*)&ins[r][c]     = v0;
        *(f32x4*)&ins[r][c + 4] = v1;
    }
    __syncthreads();

    const int lane = t & 63;
    const int h0  = __builtin_amdgcn_readfirstlane((t >> 6) * 8); // SGPR h-base
    const int row = lane & 15;
    const int d0  = (lane >> 4) * 64;    // d quarter per lane group

    float acc[8] = {0.f,0.f,0.f,0.f,0.f,0.f,0.f,0.f};
    for (int dd = 0; dd < 64; dd += 4) {
        const int d = d0 + dd;
        f32x4 v = *(const f32x4*)&ins[row][d];
        #pragma unroll
        for (int j = 0; j < 8; ++j) {
            acc[j] = fmaf(v.x, W[(d + 0) * NH + h0 + j], acc[j]);
            acc[j] = fmaf(v.y, W[(d + 1) * NH + h0 + j], acc[j]);
            acc[j] = fmaf(v.z, W[(d + 2) * NH + h0 + j], acc[j]);
            acc[j] = fmaf(v.w, W[(d + 3) * NH + h0 + j], acc[j]);
        }
    }
    #pragma unroll
    for (int j = 0; j < 8; ++j) {
        acc[j] += __shfl_xor(acc[j], 16, 64);
        acc[j] += __shfl_xor(acc[j], 32, 64);
    }
    if ((lane >> 4) == 0) {
        float* o = outp + (size_t)(rowbase + row) * NH + h0;
        f32x4 o0 = { acc[0]*SCALE2, acc[1]*SCALE2, acc[2]*SCALE2, acc[3]*SCALE2 };
        f32x4 o1 = { acc[4]*SCALE2, acc[5]*SCALE2, acc[6]*SCALE2, acc[7]*SCALE2 };
        *(f32x4*)(o)     = o0;
        *(f32x4*)(o + 4) = o1;
    }
}

// ---------------- fused score + softmax + PV
// grid = NB*(NQ/QT) = 512 blocks, 512 threads (8 waves). Wave w owns q-row w.
__global__ __launch_bounds__(512, 4) void attn_kernel(
    const float* __restrict__ qp, const float* __restrict__ kp,
    const float* __restrict__ value, const unsigned char* __restrict__ mask,
    const float* __restrict__ w_v, float* __restrict__ out)
{
    // kt double buffer; reused as paccs[3][QT][ND] (24.0 KB <= 32.5 KB) in epilogue
    __shared__ float kt_raw[2 * NH * (KT + 1)];
    __shared__ float qs[QT][NH];
    __shared__ float wv[NH];
    __shared__ float ps[QT][NK];

    const int t    = threadIdx.x;
    const int lane = t & 63;
    const int w    = __builtin_amdgcn_readfirstlane(t >> 6);  // wave id = row id
    const int b    = blockIdx.x >> 6;
    const int q0   = (blockIdx.x & 63) * QT;

    qs[t >> 6][t & 63] = qp[((size_t)(b * NQ + q0 + (t >> 6))) * NH + (t & 63)];
    if (t < NH) wv[t] = w_v[t];

    const float* kpb = kp + (size_t)b * NK * NH;

    // stage k-tile 0 into buffer 0 (wave w loads rows {w, 8+w, ..., 56+w})
    #pragma unroll
    for (int j = 0; j < 8; ++j)
        kt_raw[lane * (KT + 1) + 8 * j + w] = kpb[(size_t)(8 * j + w) * NH + lane];
    __syncthreads();

    // wsum = sum_h w_v[h]
    float wsv = wv[lane];
    #pragma unroll
    for (int off = 32; off; off >>= 1) wsv += __shfl_xor(wsv, off, 64);
    const float wsum = wsv;

    // ---- score: s = wsum - 2 * sum_h w_h * rcp(1 + exp2(q'+k'))
    float s[8];
    for (int c = 0; c < 8; ++c) {
        if (c < 7) {   // prefetch next tile into the other buffer
            const int buf = (c + 1) & 1;
            #pragma unroll
            for (int j = 0; j < 8; ++j)
                kt_raw[buf * NH * (KT + 1) + lane * (KT + 1) + 8 * j + w] =
                    kpb[(size_t)((c + 1) * KT + 8 * j + w) * NH + lane];
        }
        const float* K = &kt_raw[(c & 1) * NH * (KT + 1)];
        float a = 0.f;
        #pragma unroll
        for (int h = 0; h < NH; h += 4) {
            f32x4 q4 = *(const f32x4*)&qs[w][h];
            f32x4 w4 = *(const f32x4*)&wv[h];
            a = fmaf(w4.x, RCP(1.f + EXP2(q4.x + K[(h + 0) * (KT + 1) + lane])), a);
            a = fmaf(w4.y, RCP(1.f + EXP2(q4.y + K[(h + 1) * (KT + 1) + lane])), a);
            a = fmaf(w4.z, RCP(1.f + EXP2(q4.z + K[(h + 2) * (KT + 1) + lane])), a);
            a = fmaf(w4.w, RCP(1.f + EXP2(q4.w + K[(h + 3) * (KT + 1) + lane])), a);
        }
        s[c] = fmaf(-2.f, a, wsum);
        __syncthreads();
    }

    // ---- mask + in-register softmax (wave-wide shuffle reductions)
    const unsigned char* mrow = mask + (size_t)(b * NQ + q0 + w) * NK + lane;
    #pragma unroll
    for (int c = 0; c < 8; ++c)
        if (mrow[c * 64]) s[c] = -__builtin_inff();

    float m = s[0];
    #pragma unroll
    for (int c = 1; c < 8; ++c) m = fmaxf(m, s[c]);
    #pragma unroll
    for (int off = 32; off; off >>= 1) m = fmaxf(m, __shfl_xor(m, off, 64));

    float p[8], sum = 0.f;
    #pragma unroll
    for (int c = 0; c < 8; ++c) { p[c] = EXP2((s[c] - m) * LOG2E); sum += p[c]; }
    #pragma unroll
    for (int off = 32; off; off >>= 1) sum += __shfl_xor(sum, off, 64);
    const float rinv = 1.0f / sum;
    #pragma unroll
    for (int c = 0; c < 8; ++c) ps[w][c * 64 + lane] = p[c] * rinv;   // pre-normalized
    __syncthreads();

    // ---- PV: wave = (k-quarter, d-half); lane owns float2 of d -> v_pk_fma_f32
    const int kq   = w >> 1;            // 0..3
    const int dh   = w & 1;             // 0..1
    const int dcol = dh * 128 + 2 * lane;
    f32x2 acc[QT];
    #pragma unroll
    for (int r = 0; r < QT; ++r) acc[r] = (f32x2){0.f, 0.f};

    const float* vb = value + ((size_t)b * NK + kq * 128) * ND + dcol;
    for (int kk = 0; kk < 128; kk += 4) {
        float pv[QT][4];
        #pragma unroll
        for (int r = 0; r < QT; ++r)
            *(f32x4*)pv[r] = *(const f32x4*)&ps[r][kq * 128 + kk];   // uniform b128
        #pragma unroll
        for (int u = 0; u < 4; ++u) {
            f32x2 v = *(const f32x2*)(vb + (size_t)(kk + u) * ND);
            #pragma unroll
            for (int r = 0; r < QT; ++r) {
                f32x2 pvv = { pv[r][u], pv[r][u] };
                acc[r] = __builtin_elementwise_fma(pvv, v, acc[r]);
            }
        }
    }

    // ---- cross-wave reduce over k-quarters (kt_raw reused; all kt reads done)
    float* paccs = kt_raw;   // [3][QT][ND]
    if (kq > 0) {
        float* pw = paccs + (size_t)(kq - 1) * QT * ND + dcol;
        #pragma unroll
        for (int r = 0; r < QT; ++r)
            *(f32x2*)(pw + r * ND) = acc[r];
    }
    __syncthreads();
    if (kq == 0) {
        #pragma unroll
        for (int r = 0; r < QT; ++r) {
            f32x2 a2 = acc[r];
            #pragma unroll
            for (int j = 0; j < 3; ++j)
                a2 += *(const f32x2*)&paccs[(size_t)(j * QT + r) * ND + dcol];
            *(f32x2*)(out + (size_t)(b * NQ + q0 + r) * ND + dcol) = a2;
        }
    }
}

extern "C" void kernel_launch(void* const* d_in, const int* in_sizes, int n_in,
                              void* d_out, int out_size, void* d_ws, size_t ws_size,
                              hipStream_t stream) {
    const float* key   = (const float*)d_in[0];
    const float* query = (const float*)d_in[1];
    const float* value = (const float*)d_in[2];
    const unsigned char* mask = (const unsigned char*)d_in[3];
    const float* Wk  = (const float*)d_in[4];
    const float* Wq  = (const float*)d_in[5];
    const float* w_v = (const float*)d_in[6];
    float* out = (float*)d_out;

    float* qp = (float*)d_ws;              // [NB*NQ, NH]
    float* kp = qp + NB * NQ * NH;         // [NB*NK, NH]

    proj_kernel<<<512, 512, 0, stream>>>(query, key, Wq, Wk, qp, kp);
    attn_kernel<<<NB * (NQ / QT), 512, 0, stream>>>(qp, kp, value, mask, w_v, out);
}

// Round 3
// 61.256 us; speedup vs baseline: 1.9348x; 1.1541x over previous
//
#include <hip/hip_runtime.h>
#include <math.h>

#define NB 8
#define NQ 512
#define NK 512
#define NH 64
#define ND 256
#define QT 8     // q rows per attn block; 8 waves of 512-thr block

typedef float f32x2 __attribute__((ext_vector_type(2)));
typedef float f32x4 __attribute__((ext_vector_type(4)));

#define EXP2(x) __builtin_amdgcn_exp2f(x)
#define RCP(x)  __builtin_amdgcn_rcpf(x)
#define SCALE2 2.8853900817779268f   // 2*log2(e) folded into projections
#define LOG2E  1.4426950408889634f

// ---------------- projection + exp2: Eq[b,q,h] = exp2(clamp(S2*(query@Wq)))
//                  Ekp[b,h,k]        = exp2(clamp(S2*(key@Wk)))   (transposed!)
// 512 blocks x 256 thr; 16 rows/block; blocks >=256 handle key rows.
__global__ __launch_bounds__(256, 4) void proj_kernel(
    const float* __restrict__ query, const float* __restrict__ key,
    const float* __restrict__ Wq, const float* __restrict__ Wk,
    float* __restrict__ Eq, float* __restrict__ Ekp)
{
    __shared__ float Ws[ND * NH];  // 64 KB, linear
    const int t = threadIdx.x;
    const bool isK = blockIdx.x >= 256;
    const float* __restrict__ in = isK ? key : query;
    const float* __restrict__ W  = isK ? Wk : Wq;
    const int rowbase = (blockIdx.x & 255) * 16;

    for (int i = t * 4; i < ND * NH; i += 256 * 4)
        *(f32x4*)&Ws[i] = *(const f32x4*)&W[i];
    __syncthreads();

    const int lane = t & 63;
    const int w = __builtin_amdgcn_readfirstlane(t >> 6);   // wave id 0..3
    const int r0 = rowbase + 4 * w;
    const float* __restrict__ p0 = in + (size_t)(r0 + 0) * ND;
    const float* __restrict__ p1 = in + (size_t)(r0 + 1) * ND;
    const float* __restrict__ p2 = in + (size_t)(r0 + 2) * ND;
    const float* __restrict__ p3 = in + (size_t)(r0 + 3) * ND;

    float a0 = 0.f, a1 = 0.f, a2 = 0.f, a3 = 0.f;
    for (int d0 = 0; d0 < ND; d0 += 8) {
        #pragma unroll
        for (int dd = 0; dd < 8; ++dd) {
            const float wsv = Ws[(d0 + dd) * NH + lane];   // vector b32, conflict-free
            a0 = fmaf(p0[d0 + dd], wsv, a0);               // scalar (uniform) operand
            a1 = fmaf(p1[d0 + dd], wsv, a1);
            a2 = fmaf(p2[d0 + dd], wsv, a2);
            a3 = fmaf(p3[d0 + dd], wsv, a3);
        }
    }
    float e[4];
    e[0] = a0; e[1] = a1; e[2] = a2; e[3] = a3;
    #pragma unroll
    for (int j = 0; j < 4; ++j) {
        float x = fminf(fmaxf(e[j] * SCALE2, -40.f), 40.f);
        e[j] = EXP2(x);
    }
    if (!isK) {
        #pragma unroll
        for (int j = 0; j < 4; ++j)
            Eq[(size_t)(r0 + j) * NH + lane] = e[j];
    } else {
        #pragma unroll
        for (int j = 0; j < 4; ++j) {
            const int g = r0 + j;
            const int b = g >> 9, kk = g & 511;
            Ekp[((size_t)b * NH + lane) * NK + kk] = e[j];
        }
    }
}

// ---------------- fused score + softmax + PV
// grid = NB*(NQ/QT) = 512 blocks, 512 threads (8 waves).
// Wave ws owns k-slice [64*ws, 64*ws+64); computes all QT rows for its slice.
__global__ __launch_bounds__(512, 4) void attn_kernel(
    const float* __restrict__ Eq, const float* __restrict__ Ekp,
    const float* __restrict__ value, const unsigned char* __restrict__ mask,
    const float* __restrict__ w_v, float* __restrict__ out)
{
    __shared__ float ekb[2][4][516];     // 16.5 KB  h-chunk double buffer
    __shared__ float qEq[QT][NH];        // 2 KB
    __shared__ float qFq[QT][NH];        // 2 KB   Fq[h] = w_v[h^1]*Eq[h]
    __shared__ float w01s[NH / 2];       // 128 B
    __shared__ float ps[NK][12];         // 24.75 KB  probs, k-major (rows 0..7)
    __shared__ float pacc[3][QT][ND];    // 24 KB    PV partials
    __shared__ float redm[QT][8];        // 256 B
    __shared__ float reds[QT][8];        // 256 B

    const int t    = threadIdx.x;
    const int lane = t & 63;
    const int ws   = __builtin_amdgcn_readfirstlane(t >> 6);
    const int b    = blockIdx.x >> 6;
    const int q0   = (blockIdx.x & 63) * QT;

    // prologue: per-row tables
    {
        const int r = t >> 6, h = t & 63;
        const float e = Eq[(size_t)(b * NQ + q0 + r) * NH + h];
        qEq[r][h] = e;
        qFq[r][h] = w_v[h ^ 1] * e;
    }
    if (t < 32) w01s[t] = w_v[2 * t] + w_v[2 * t + 1];

    float wl = w_v[lane];
    #pragma unroll
    for (int off = 32; off; off >>= 1) wl += __shfl_xor(wl, off, 64);
    const float wsum = wl;

    // stage h-chunk 0: wave ws stages (h' = ws>>1, k-half = ws&1)
    const float* __restrict__ ekg = Ekp + (size_t)b * NH * NK;
    const int sh = ws >> 1;
    const int sk = (ws & 1) * 256 + 4 * lane;
    {
        f32x4 v = *(const f32x4*)&ekg[(size_t)sh * NK + sk];
        *(f32x4*)&ekb[0][sh][sk] = v;
    }
    __syncthreads();

    // ---- score: acc[r] = sum over h-pairs of N*rcp(D)
    const int kidx = (ws << 6) + lane;   // this thread's k
    float acc[QT] = {0.f,0.f,0.f,0.f,0.f,0.f,0.f,0.f};

    for (int hc = 0; hc < 16; ++hc) {
        const int buf = hc & 1;
        if (hc < 15) {   // prefetch next chunk
            f32x4 v = *(const f32x4*)&ekg[(size_t)(4 * (hc + 1) + sh) * NK + sk];
            *(f32x4*)&ekb[buf ^ 1][sh][sk] = v;
        }
        const float ek0 = ekb[buf][0][kidx];
        const float ek1 = ekb[buf][1][kidx];
        const float ek2 = ekb[buf][2][kidx];
        const float ek3 = ekb[buf][3][kidx];
        const float w01a = w01s[2 * hc];
        const float w01b = w01s[2 * hc + 1];
        #pragma unroll
        for (int r = 0; r < QT; ++r) {
            const f32x4 eq = *(const f32x4*)&qEq[r][4 * hc];
            const f32x4 fq = *(const f32x4*)&qFq[r][4 * hc];
            {
                const float t0 = eq.x * ek0, t1 = eq.y * ek1;
                const float u  = 1.f + (t0 + t1);
                const float dd = fmaf(t0, t1, u);
                float n = fmaf(fq.y, ek1, w01a);
                n = fmaf(fq.x, ek0, n);
                acc[r] = fmaf(n, RCP(dd), acc[r]);
            }
            {
                const float t2 = eq.z * ek2, t3 = eq.w * ek3;
                const float u2 = 1.f + (t2 + t3);
                const float d2 = fmaf(t2, t3, u2);
                float n2 = fmaf(fq.w, ek3, w01b);
                n2 = fmaf(fq.z, ek2, n2);
                acc[r] = fmaf(n2, RCP(d2), acc[r]);
            }
        }
        __syncthreads();
    }

    // ---- scores + mask
    float s[QT];
    const unsigned char* __restrict__ mb = mask + (size_t)(b * NQ + q0) * NK + kidx;
    #pragma unroll
    for (int r = 0; r < QT; ++r) {
        s[r] = fmaf(-2.f, acc[r], wsum);
        if (mb[(size_t)r * NK]) s[r] = -__builtin_inff();
    }

    // ---- softmax: wave-local reduce then cross-wave via LDS
    float lm[QT];
    #pragma unroll
    for (int r = 0; r < QT; ++r) {
        float m = s[r];
        #pragma unroll
        for (int off = 32; off; off >>= 1) m = fmaxf(m, __shfl_xor(m, off, 64));
        lm[r] = m;
    }
    if (lane == 0) {
        #pragma unroll
        for (int r = 0; r < QT; ++r) redm[r][ws] = lm[r];
    }
    __syncthreads();
    float gm[QT];
    #pragma unroll
    for (int r = 0; r < QT; ++r) {
        const f32x4 ga = *(const f32x4*)&redm[r][0];
        const f32x4 gb = *(const f32x4*)&redm[r][4];
        gm[r] = fmaxf(fmaxf(fmaxf(ga.x, ga.y), fmaxf(ga.z, ga.w)),
                      fmaxf(fmaxf(gb.x, gb.y), fmaxf(gb.z, gb.w)));
    }
    float p[QT], lsum[QT];
    #pragma unroll
    for (int r = 0; r < QT; ++r) {
        p[r] = EXP2((s[r] - gm[r]) * LOG2E);
        float ssum = p[r];
        #pragma unroll
        for (int off = 32; off; off >>= 1) ssum += __shfl_xor(ssum, off, 64);
        lsum[r] = ssum;
    }
    if (lane == 0) {
        #pragma unroll
        for (int r = 0; r < QT; ++r) reds[r][ws] = lsum[r];
    }
    __syncthreads();
    #pragma unroll
    for (int r = 0; r < QT; ++r) {
        const f32x4 ga = *(const f32x4*)&reds[r][0];
        const f32x4 gb = *(const f32x4*)&reds[r][4];
        const float gsum = ((ga.x + ga.y) + (ga.z + ga.w)) +
                           ((gb.x + gb.y) + (gb.z + gb.w));
        p[r] = p[r] * (1.0f / gsum);    // pre-normalized prob
    }
    {
        f32x4 pa = { p[0], p[1], p[2], p[3] };
        f32x4 pb = { p[4], p[5], p[6], p[7] };
        *(f32x4*)&ps[kidx][0] = pa;
        *(f32x4*)&ps[kidx][4] = pb;
    }
    __syncthreads();

    // ---- PV: wave = (k-quarter, d-half); lane owns f32x2 of d
    const int kq = ws >> 1, dh = ws & 1;
    const int dbase = dh * 128 + 2 * lane;
    f32x2 acc2[QT];
    #pragma unroll
    for (int r = 0; r < QT; ++r) acc2[r] = (f32x2){0.f, 0.f};

    const float* __restrict__ vb = value + ((size_t)b * NK + kq * 128) * ND + dbase;
    const float* __restrict__ psb = &ps[kq * 128][0];
    for (int kk = 0; kk < 128; kk += 2) {
        const f32x4 pa0 = *(const f32x4*)&psb[kk * 12 + 0];
        const f32x4 pb0 = *(const f32x4*)&psb[kk * 12 + 4];
        const f32x2 v0  = *(const f32x2*)&vb[(size_t)kk * ND];
        const f32x4 pa1 = *(const f32x4*)&psb[(kk + 1) * 12 + 0];
        const f32x4 pb1 = *(const f32x4*)&psb[(kk + 1) * 12 + 4];
        const f32x2 v1  = *(const f32x2*)&vb[(size_t)(kk + 1) * ND];
        acc2[0] = __builtin_elementwise_fma((f32x2){pa0.x, pa0.x}, v0, acc2[0]);
        acc2[1] = __builtin_elementwise_fma((f32x2){pa0.y, pa0.y}, v0, acc2[1]);
        acc2[2] = __builtin_elementwise_fma((f32x2){pa0.z, pa0.z}, v0, acc2[2]);
        acc2[3] = __builtin_elementwise_fma((f32x2){pa0.w, pa0.w}, v0, acc2[3]);
        acc2[4] = __builtin_elementwise_fma((f32x2){pb0.x, pb0.x}, v0, acc2[4]);
        acc2[5] = __builtin_elementwise_fma((f32x2){pb0.y, pb0.y}, v0, acc2[5]);
        acc2[6] = __builtin_elementwise_fma((f32x2){pb0.z, pb0.z}, v0, acc2[6]);
        acc2[7] = __builtin_elementwise_fma((f32x2){pb0.w, pb0.w}, v0, acc2[7]);
        acc2[0] = __builtin_elementwise_fma((f32x2){pa1.x, pa1.x}, v1, acc2[0]);
        acc2[1] = __builtin_elementwise_fma((f32x2){pa1.y, pa1.y}, v1, acc2[1]);
        acc2[2] = __builtin_elementwise_fma((f32x2){pa1.z, pa1.z}, v1, acc2[2]);
        acc2[3] = __builtin_elementwise_fma((f32x2){pa1.w, pa1.w}, v1, acc2[3]);
        acc2[4] = __builtin_elementwise_fma((f32x2){pb1.x, pb1.x}, v1, acc2[4]);
        acc2[5] = __builtin_elementwise_fma((f32x2){pb1.y, pb1.y}, v1, acc2[5]);
        acc2[6] = __builtin_elementwise_fma((f32x2){pb1.z, pb1.z}, v1, acc2[6]);
        acc2[7] = __builtin_elementwise_fma((f32x2){pb1.w, pb1.w}, v1, acc2[7]);
    }

    // ---- cross-wave reduce over 4 k-quarters
    if (kq > 0) {
        #pragma unroll
        for (int r = 0; r < QT; ++r)
            *(f32x2*)&pacc[kq - 1][r][dbase] = acc2[r];
    }
    __syncthreads();
    if (kq == 0) {
        #pragma unroll
        for (int r = 0; r < QT; ++r) {
            f32x2 a2 = acc2[r];
            a2 += *(const f32x2*)&pacc[0][r][dbase];
            a2 += *(const f32x2*)&pacc[1][r][dbase];
            a2 += *(const f32x2*)&pacc[2][r][dbase];
            *(f32x2*)&out[(size_t)(b * NQ + q0 + r) * ND + dbase] = a2;
        }
    }
}

extern "C" void kernel_launch(void* const* d_in, const int* in_sizes, int n_in,
                              void* d_out, int out_size, void* d_ws, size_t ws_size,
                              hipStream_t stream) {
    const float* key   = (const float*)d_in[0];
    const float* query = (const float*)d_in[1];
    const float* value = (const float*)d_in[2];
    const unsigned char* mask = (const unsigned char*)d_in[3];
    const float* Wk  = (const float*)d_in[4];
    const float* Wq  = (const float*)d_in[5];
    const float* w_v = (const float*)d_in[6];
    float* out = (float*)d_out;

    float* Eq  = (float*)d_ws;                 // [NB*NQ, NH]
    float* Ekp = Eq + (size_t)NB * NQ * NH;    // [NB, NH, NK]

    proj_kernel<<<512, 256, 0, stream>>>(query, key, Wq, Wk, Eq, Ekp);
    attn_kernel<<<NB * (NQ / QT), 512, 0, stream>>>(Eq, Ekp, value, mask, w_v, out);
}

// Round 4
// 57.435 us; speedup vs baseline: 2.0635x; 1.0665x over previous
//
#include <hip/hip_runtime.h>
#include <math.h>

#define NB 8
#define NQ 512
#define NK 512
#define NH 64
#define ND 256
#define QT 8     // q rows per attn block

typedef float f32x2 __attribute__((ext_vector_type(2)));
typedef float f32x4 __attribute__((ext_vector_type(4)));

#define EXP2(x) __builtin_amdgcn_exp2f(x)
#define RCP(x)  __builtin_amdgcn_rcpf(x)
#define SCALE2 2.8853900817779268f   // 2*log2(e) folded into projections
#define LOG2E  1.4426950408889634f

static __device__ __forceinline__ f32x2 sp2(float v) { return (f32x2){v, v}; }
#define FMA2(a, b, c) __builtin_elementwise_fma((a), (b), (c))

// ---------------- projection + exp2: Eq[b,q,h] = exp2(clamp(S2*(query@Wq)))
//                  Ekp[b,h,k]        = exp2(clamp(S2*(key@Wk)))   (transposed)
// 1024 blocks x 256 thr (4 waves); 8 rows/block; blocks >=512 handle key rows.
// Rows staged in LDS (b128 broadcast reads); W streamed from L2, h = lane.
__global__ __launch_bounds__(256, 8) void proj_kernel(
    const float* __restrict__ query, const float* __restrict__ key,
    const float* __restrict__ Wq, const float* __restrict__ Wk,
    float* __restrict__ Eq, float* __restrict__ Ekp)
{
    __shared__ __align__(16) float ins[8][260];
    __shared__ float pacc[3][8][64];
    const int t = threadIdx.x;
    const bool isK = blockIdx.x >= 512;
    const float* __restrict__ in = isK ? key : query;
    const float* __restrict__ W  = isK ? Wk : Wq;
    const int rowbase = (blockIdx.x & 511) * 8;

    {   // stage 8 rows x 256 floats
        const int r = t >> 5, c = (t & 31) * 8;
        const float* src = in + (size_t)(rowbase + r) * ND + c;
        *(f32x4*)&ins[r][c]     = *(const f32x4*)src;
        *(f32x4*)&ins[r][c + 4] = *(const f32x4*)(src + 4);
    }
    __syncthreads();

    const int lane = t & 63;
    const int w    = t >> 6;           // wave id 0..3 -> d-slice
    const int d0   = w * 64;

    float acc[8] = {0.f,0.f,0.f,0.f,0.f,0.f,0.f,0.f};
    #pragma unroll 4
    for (int dq = 0; dq < 64; dq += 4) {
        const int d = d0 + dq;
        const float w0 = W[(size_t)(d + 0) * NH + lane];
        const float w1 = W[(size_t)(d + 1) * NH + lane];
        const float w2 = W[(size_t)(d + 2) * NH + lane];
        const float w3 = W[(size_t)(d + 3) * NH + lane];
        #pragma unroll
        for (int r = 0; r < 8; ++r) {
            const f32x4 rv = *(const f32x4*)&ins[r][d];   // wave-uniform b128
            acc[r] = fmaf(rv.x, w0, acc[r]);
            acc[r] = fmaf(rv.y, w1, acc[r]);
            acc[r] = fmaf(rv.z, w2, acc[r]);
            acc[r] = fmaf(rv.w, w3, acc[r]);
        }
    }
    if (w > 0) {
        #pragma unroll
        for (int r = 0; r < 8; ++r) pacc[w - 1][r][lane] = acc[r];
    }
    __syncthreads();
    if (w == 0) {
        #pragma unroll
        for (int r = 0; r < 8; ++r) {
            const float a = acc[r] + pacc[0][r][lane] + pacc[1][r][lane]
                                   + pacc[2][r][lane];
            const float x = fminf(fmaxf(a * SCALE2, -30.f), 30.f);
            const float e = EXP2(x);
            const int g = rowbase + r;
            if (!isK) {
                Eq[(size_t)g * NH + lane] = e;
            } else {
                const int b = g >> 9, kk = g & 511;
                Ekp[((size_t)b * NH + lane) * NK + kk] = e;
            }
        }
    }
}

// ---------------- fused score + softmax + PV
// grid = NB*(NQ/QT) = 512 blocks, 1024 threads (16 waves) -> 2 blocks/CU = 100% occ.
// Wave ws: k-quarter kq4 = ws&3, row-group rg = ws>>2 (rows 2rg, 2rg+1).
// Each thread: 2 adjacent k (f32x2 packed) x 2 rows.
__global__ __launch_bounds__(1024, 8) void attn_kernel(
    const float* __restrict__ Eq, const float* __restrict__ Ekp,
    const float* __restrict__ value, const unsigned char* __restrict__ mask,
    const float* __restrict__ w_v, float* __restrict__ out)
{
    // smA: [ ekb 2*4*516 | qEq 8*64 | qFq 8*64 | w01 32 ] = 5184 f, reused as
    //      pacc[7][8][256] = 14336 f after softmax barrier.
    __shared__ __align__(16) float smA[14336];   // 57344 B
    __shared__ __align__(16) float ps[QT][516];  // 16512 B probs (pre-normalized)
    __shared__ __align__(16) float reds[QT][4];  // row-sum partials

    float* const ekb = smA;            // [2][4][516]
    float* const qEq = smA + 4128;     // [8][64]
    float* const qFq = smA + 4640;     // [8][64]  Fq[h] = w_v[h^1]*Eq[h]
    float* const w01 = smA + 5152;     // [32]

    const int t    = threadIdx.x;
    const int lane = t & 63;
    const int ws   = t >> 6;                 // 0..15
    const int b    = blockIdx.x >> 6;
    const int q0   = (blockIdx.x & 63) * QT;

    if (t < 512) {
        const int r = t >> 6, h = t & 63;
        const float e = Eq[(size_t)(b * NQ + q0 + r) * NH + h];
        qEq[r * 64 + h] = e;
        qFq[r * 64 + h] = w_v[h ^ 1] * e;
    }
    if (t < 32) w01[t] = w_v[2 * t] + w_v[2 * t + 1];

    float wl = w_v[lane];
    #pragma unroll
    for (int off = 32; off; off >>= 1) wl += __shfl_xor(wl, off, 64);
    const float wsumL = wl * LOG2E;

    const float* __restrict__ ekg = Ekp + (size_t)b * NH * NK;
    const int sh = t >> 8;             // 0..3 (h within chunk)
    const int sk = (t & 255) * 2;      // k pair
    *(f32x2*)&ekb[sh * 516 + sk] = *(const f32x2*)&ekg[(size_t)sh * NK + sk];
    __syncthreads();

    const int kq4 = ws & 3;
    const int rg  = ws >> 2;
    const int kp  = kq4 * 64 + lane;   // kpack 0..255; k = {2kp, 2kp+1}
    const int r0  = 2 * rg;

    f32x2 acc0 = {0.f, 0.f}, acc1 = {0.f, 0.f};

    // score: acc = sum over 4h groups of N4 * rcp(D4), packed over 2 k
    for (int hc = 0; hc < 16; ++hc) {
        const int buf = hc & 1;
        if (hc < 15) {
            *(f32x2*)&ekb[(buf ^ 1) * 2064 + sh * 516 + sk] =
                *(const f32x2*)&ekg[(size_t)(4 * (hc + 1) + sh) * NK + sk];
        }
        const float* Kb = &ekb[buf * 2064];
        const f32x2 ek0 = *(const f32x2*)&Kb[0 * 516 + 2 * kp];
        const f32x2 ek1 = *(const f32x2*)&Kb[1 * 516 + 2 * kp];
        const f32x2 ek2 = *(const f32x2*)&Kb[2 * 516 + 2 * kp];
        const f32x2 ek3 = *(const f32x2*)&Kb[3 * 516 + 2 * kp];
        const float w01a = w01[2 * hc], w01b = w01[2 * hc + 1];

#define SCORE4(EQV, FQV, ACCR)                                              \
        {                                                                   \
            const f32x2 t0 = ek0 * (EQV).x;                                 \
            const f32x2 t1 = ek1 * (EQV).y;                                 \
            const f32x2 ua = t0 + t1 + 1.0f;                                \
            const f32x2 dda = FMA2(t0, t1, ua);                             \
            f32x2 na = FMA2(sp2((FQV).x), ek0, sp2(w01a));                  \
            na = FMA2(sp2((FQV).y), ek1, na);                               \
            const f32x2 t2 = ek2 * (EQV).z;                                 \
            const f32x2 t3 = ek3 * (EQV).w;                                 \
            const f32x2 ub = t2 + t3 + 1.0f;                                \
            const f32x2 ddb = FMA2(t2, t3, ub);                             \
            f32x2 nb = FMA2(sp2((FQV).z), ek2, sp2(w01b));                  \
            nb = FMA2(sp2((FQV).w), ek3, nb);                               \
            const f32x2 Dv = dda * ddb;                                     \
            f32x2 Nv = na * ddb;                                            \
            Nv = FMA2(nb, dda, Nv);                                         \
            const f32x2 rD = { RCP(Dv.x), RCP(Dv.y) };                      \
            ACCR = FMA2(Nv, rD, ACCR);                                      \
        }
        {
            const f32x4 eqA = *(const f32x4*)&qEq[(r0 + 0) * 64 + 4 * hc];
            const f32x4 fqA = *(const f32x4*)&qFq[(r0 + 0) * 64 + 4 * hc];
            SCORE4(eqA, fqA, acc0);
            const f32x4 eqB = *(const f32x4*)&qEq[(r0 + 1) * 64 + 4 * hc];
            const f32x4 fqB = *(const f32x4*)&qFq[(r0 + 1) * 64 + 4 * hc];
            SCORE4(eqB, fqB, acc1);
        }
        __syncthreads();
    }

    // ---- mask + softmax (no max-subtraction: |score| <= sum|w| ~ 6.4)
    const unsigned char* mrow0 = mask + (size_t)(b * NQ + q0 + r0) * NK + 2 * kp;
    f32x2 arg0 = FMA2(acc0, sp2(-2.f * LOG2E), sp2(wsumL));
    f32x2 arg1 = FMA2(acc1, sp2(-2.f * LOG2E), sp2(wsumL));
    const unsigned short m0 = *(const unsigned short*)mrow0;
    const unsigned short m1 = *(const unsigned short*)(mrow0 + NK);
    if (m0 & 0x00ff) arg0.x = -__builtin_inff();
    if (m0 & 0xff00) arg0.y = -__builtin_inff();
    if (m1 & 0x00ff) arg1.x = -__builtin_inff();
    if (m1 & 0xff00) arg1.y = -__builtin_inff();

    f32x2 p0 = { EXP2(arg0.x), EXP2(arg0.y) };
    f32x2 p1 = { EXP2(arg1.x), EXP2(arg1.y) };
    float h0 = p0.x + p0.y, h1 = p1.x + p1.y;
    #pragma unroll
    for (int off = 32; off; off >>= 1) {
        h0 += __shfl_xor(h0, off, 64);
        h1 += __shfl_xor(h1, off, 64);
    }
    if (lane == 0) { reds[r0][kq4] = h0; reds[r0 + 1][kq4] = h1; }
    __syncthreads();
    {
        const f32x4 s0 = *(const f32x4*)&reds[r0][0];
        const f32x4 s1 = *(const f32x4*)&reds[r0 + 1][0];
        p0 = p0 * RCP((s0.x + s0.y) + (s0.z + s0.w));
        p1 = p1 * RCP((s1.x + s1.y) + (s1.z + s1.w));
    }
    *(f32x2*)&ps[r0][2 * kp]     = p0;
    *(f32x2*)&ps[r0 + 1][2 * kp] = p1;
    __syncthreads();    // also fences smA reuse as pacc

    // ---- PV: wave = (kq 0..7, dh 0..1); lane owns f32x2 of d
    const int kq   = ws >> 1;
    const int dh   = ws & 1;
    const int dcol = dh * 128 + 2 * lane;
    f32x2 a[QT];
    #pragma unroll
    for (int r = 0; r < QT; ++r) a[r] = (f32x2){0.f, 0.f};

    const float* __restrict__ vb = value + ((size_t)b * NK + kq * 64) * ND + dcol;
    for (int kk = 0; kk < 64; kk += 2) {
        f32x2 pr[QT];
        #pragma unroll
        for (int r = 0; r < QT; ++r)
            pr[r] = *(const f32x2*)&ps[r][kq * 64 + kk];   // uniform b64
        const f32x2 v0 = *(const f32x2*)&vb[(size_t)kk * ND];
        const f32x2 v1 = *(const f32x2*)&vb[(size_t)(kk + 1) * ND];
        #pragma unroll
        for (int r = 0; r < QT; ++r) {
            a[r] = FMA2(sp2(pr[r].x), v0, a[r]);
            a[r] = FMA2(sp2(pr[r].y), v1, a[r]);
        }
    }

    float* const pacc = smA;   // [7][8][256]
    if (kq > 0) {
        #pragma unroll
        for (int r = 0; r < QT; ++r)
            *(f32x2*)&pacc[((kq - 1) * QT + r) * ND + dcol] = a[r];
    }
    __syncthreads();
    if (kq == 0) {
        #pragma unroll
        for (int r = 0; r < QT; ++r) {
            f32x2 v = a[r];
            #pragma unroll
            for (int j = 0; j < 7; ++j)
                v += *(const f32x2*)&pacc[(j * QT + r) * ND + dcol];
            *(f32x2*)&out[(size_t)(b * NQ + q0 + r) * ND + dcol] = v;
        }
    }
}

extern "C" void kernel_launch(void* const* d_in, const int* in_sizes, int n_in,
                              void* d_out, int out_size, void* d_ws, size_t ws_size,
                              hipStream_t stream) {
    const float* key   = (const float*)d_in[0];
    const float* query = (const float*)d_in[1];
    const float* value = (const float*)d_in[2];
    const unsigned char* mask = (const unsigned char*)d_in[3];
    const float* Wk  = (const float*)d_in[4];
    const float* Wq  = (const float*)d_in[5];
    const float* w_v = (const float*)d_in[6];
    float* out = (float*)d_out;

    float* Eq  = (float*)d_ws;                 // [NB*NQ, NH]
    float* Ekp = Eq + (size_t)NB * NQ * NH;    // [NB, NH, NK]

    proj_kernel<<<1024, 256, 0, stream>>>(query, key, Wq, Wk, Eq, Ekp);
    attn_kernel<<<NB * (NQ / QT), 1024, 0, stream>>>(Eq, Ekp, value, mask, w_v, out);
}

// Round 9
// 48.591 us; speedup vs baseline: 2.4391x; 1.1820x over previous
//
#include <hip/hip_runtime.h>
#include <math.h>

#define NB 8
#define NQ 512
#define NK 512
#define NH 64
#define ND 256
#define QT 8     // q rows per attn block

typedef float f32x2 __attribute__((ext_vector_type(2)));
typedef float f32x4 __attribute__((ext_vector_type(4)));

#define EXP2(x) __builtin_amdgcn_exp2f(x)
#define RCP(x)  __builtin_amdgcn_rcpf(x)
#define SCALE2 2.8853900817779268f   // 2*log2(e) folded into projections
#define LOG2E  1.4426950408889634f

static __device__ __forceinline__ f32x2 sp2(float v) { return (f32x2){v, v}; }
static __device__ __forceinline__ f32x2 fma2(f32x2 a, f32x2 b, f32x2 c) {
    return __builtin_elementwise_fma(a, b, c);
}
static __device__ __forceinline__ f32x2 mk2(float x, float y) {
    return (f32x2){x, y};
}

// ---------------- projection + exp2: Eq[b,q,h] = exp2(clamp(S2*(query@Wq)))
//                  Ekp[b,h,k]        = exp2(clamp(S2*(key@Wk)))   (transposed)
// 1024 blocks x 256 thr (4 waves); 8 rows/block; blocks >=512 handle key rows.
// Rows staged TRANSPOSED in LDS so row-pairs pack into f32x2; W from L2.
__global__ __launch_bounds__(256, 4) void proj_kernel(
    const float* __restrict__ query, const float* __restrict__ key,
    const float* __restrict__ Wq, const float* __restrict__ Wk,
    float* __restrict__ Eq, float* __restrict__ Ekp)
{
    __shared__ __align__(16) float insT[ND][12];   // 12 KB, b128-aligned rows
    __shared__ float pacc[3][4][NH][2];            // 6 KB wave partials
    const int t = threadIdx.x;
    const bool isK = blockIdx.x >= 512;
    const float* __restrict__ in = isK ? key : query;
    const float* __restrict__ W  = isK ? Wk : Wq;
    const int rowbase = (blockIdx.x & 511) * 8;

    {   // stage 8 rows x 256 d, transposed
        const int r = t & 7, c = (t >> 3) * 8;
        const float* src = in + (size_t)(rowbase + r) * ND + c;
        const f32x4 v0 = *(const f32x4*)src;
        const f32x4 v1 = *(const f32x4*)(src + 4);
        insT[c + 0][r] = v0.x; insT[c + 1][r] = v0.y;
        insT[c + 2][r] = v0.z; insT[c + 3][r] = v0.w;
        insT[c + 4][r] = v1.x; insT[c + 5][r] = v1.y;
        insT[c + 6][r] = v1.z; insT[c + 7][r] = v1.w;
    }
    __syncthreads();

    const int lane = t & 63;          // lane = h
    const int w    = t >> 6;          // wave = d-quarter
    const int d0   = w * 64;

    f32x2 acc[4] = {{0.f,0.f},{0.f,0.f},{0.f,0.f},{0.f,0.f}};
    for (int dd = 0; dd < 64; ++dd) {
        const int d = d0 + dd;
        const float wv = W[(size_t)d * NH + lane];         // coalesced L2
        const f32x4 rA = *(const f32x4*)&insT[d][0];       // uniform b128
        const f32x4 rB = *(const f32x4*)&insT[d][4];
        acc[0] = fma2(mk2(rA.x, rA.y), sp2(wv), acc[0]);
        acc[1] = fma2(mk2(rA.z, rA.w), sp2(wv), acc[1]);
        acc[2] = fma2(mk2(rB.x, rB.y), sp2(wv), acc[2]);
        acc[3] = fma2(mk2(rB.z, rB.w), sp2(wv), acc[3]);
    }
    if (w > 0) {
        #pragma unroll
        for (int rp = 0; rp < 4; ++rp)
            *(f32x2*)&pacc[w - 1][rp][lane][0] = acc[rp];
    }
    __syncthreads();
    if (w == 0) {
        float e[8];
        #pragma unroll
        for (int rp = 0; rp < 4; ++rp) {
            f32x2 a = acc[rp];
            a += *(const f32x2*)&pacc[0][rp][lane][0];
            a += *(const f32x2*)&pacc[1][rp][lane][0];
            a += *(const f32x2*)&pacc[2][rp][lane][0];
            e[2 * rp] = a.x; e[2 * rp + 1] = a.y;
        }
        #pragma unroll
        for (int j = 0; j < 8; ++j) {
            const float x = fminf(fmaxf(e[j] * SCALE2, -30.f), 30.f);
            e[j] = EXP2(x);
        }
        if (!isK) {
            #pragma unroll
            for (int j = 0; j < 8; ++j)
                Eq[(size_t)(rowbase + j) * NH + lane] = e[j];
        } else {
            #pragma unroll
            for (int j = 0; j < 8; ++j) {
                const int g = rowbase + j;
                const int bb = g >> 9, kk = g & 511;
                Ekp[((size_t)bb * NH + lane) * NK + kk] = e[j];
            }
        }
    }
}

// ---------------- fused score + softmax + PV
// grid = NB*(NQ/QT) = 512 blocks, 512 threads (8 waves).
// Score: wave w owns k in [64w,64w+64); thread = 1 k x 8 rows (4 f32x2 pairs).
// Ek streamed straight from L2 (coalesced, software-pipelined) — NO barriers.
__global__ __launch_bounds__(512, 4) void attn_kernel(
    const float* __restrict__ Eq, const float* __restrict__ Ekp,
    const float* __restrict__ value, const unsigned char* __restrict__ mask,
    const float* __restrict__ w_v, float* __restrict__ out)
{
    __shared__ __align__(16) float qT[NH][4][4];   // [h][rp]{eq0,eq1,fq0,fq1} 4 KB
    __shared__ float w01[32];
    __shared__ __align__(16) float ps[QT][NK];     // 16 KB pre-normalized probs
    __shared__ __align__(16) float reds[QT][8];    // wave row-sum partials
    __shared__ __align__(16) float pacc[3][4][ND]; // 12 KB PV partials (half-rounds)

    const int t    = threadIdx.x;
    const int lane = t & 63;
    const int w    = t >> 6;
    const int b    = blockIdx.x >> 6;
    const int q0   = (blockIdx.x & 63) * QT;

    {   // qT populate: wave = row (coalesced Eq read)
        const int r = w, h = lane;
        const float e = Eq[(size_t)(b * NQ + q0 + r) * NH + h];
        qT[h][r >> 1][r & 1]       = e;
        qT[h][r >> 1][2 + (r & 1)] = w_v[h ^ 1] * e;
    }
    if (t < 32) w01[t] = w_v[2 * t] + w_v[2 * t + 1];
    float wl = w_v[lane];
    #pragma unroll
    for (int off = 32; off; off >>= 1) wl += __shfl_xor(wl, off, 64);
    const float wsumL = wl * LOG2E;
    __syncthreads();

    // ---- score: thread's k column, all 8 rows
    const int k = (w << 6) + lane;
    const float* __restrict__ ekc = Ekp + (size_t)b * NH * NK + k;

    f32x2 acc[4] = {{0.f,0.f},{0.f,0.f},{0.f,0.f},{0.f,0.f}};
    float eka[4];
    #pragma unroll
    for (int j = 0; j < 4; ++j) eka[j] = ekc[(size_t)j * NK];

    for (int hc = 0; hc < 16; ++hc) {
        const float ek0 = eka[0], ek1 = eka[1], ek2 = eka[2], ek3 = eka[3];
        if (hc < 15) {   // prefetch next h-chunk (L2 latency hides under compute)
            #pragma unroll
            for (int j = 0; j < 4; ++j)
                eka[j] = ekc[(size_t)(4 * (hc + 1) + j) * NK];
        }
        const f32x2 w2 = *(const f32x2*)&w01[2 * hc];
        const int hb = 4 * hc;
        #pragma unroll
        for (int rp = 0; rp < 4; ++rp) {
            const f32x4 g0 = *(const f32x4*)&qT[hb + 0][rp][0];
            const f32x4 g1 = *(const f32x4*)&qT[hb + 1][rp][0];
            const f32x4 g2 = *(const f32x4*)&qT[hb + 2][rp][0];
            const f32x4 g3 = *(const f32x4*)&qT[hb + 3][rp][0];
            const f32x2 t0 = mk2(g0.x, g0.y) * ek0;
            const f32x2 t1 = mk2(g1.x, g1.y) * ek1;
            const f32x2 ua = t0 + t1 + 1.0f;
            const f32x2 da = fma2(t0, t1, ua);
            f32x2 na = fma2(mk2(g0.z, g0.w), sp2(ek0), sp2(w2.x));
            na = fma2(mk2(g1.z, g1.w), sp2(ek1), na);
            const f32x2 t2 = mk2(g2.x, g2.y) * ek2;
            const f32x2 t3 = mk2(g3.x, g3.y) * ek3;
            const f32x2 ub = t2 + t3 + 1.0f;
            const f32x2 db = fma2(t2, t3, ub);
            f32x2 nb = fma2(mk2(g2.z, g2.w), sp2(ek2), sp2(w2.y));
            nb = fma2(mk2(g3.z, g3.w), sp2(ek3), nb);
            const f32x2 D = da * db;
            f32x2 N = na * db;
            N = fma2(nb, da, N);
            const f32x2 rD = mk2(RCP(D.x), RCP(D.y));
            acc[rp] = fma2(N, rD, acc[rp]);
        }
    }

    // ---- mask + exp (no max-subtraction: |score| <= sum|w_h| ~ 6.4)
    float p[8];
    {
        const unsigned char* __restrict__ mb =
            mask + (size_t)(b * NQ + q0) * NK + k;
        #pragma unroll
        for (int rp = 0; rp < 4; ++rp) {
            const f32x2 arg = fma2(acc[rp], sp2(-2.f * LOG2E), sp2(wsumL));
            p[2 * rp]     = mb[(size_t)(2 * rp) * NK]     ? -__builtin_inff() : arg.x;
            p[2 * rp + 1] = mb[(size_t)(2 * rp + 1) * NK] ? -__builtin_inff() : arg.y;
        }
        #pragma unroll
        for (int r = 0; r < 8; ++r) p[r] = EXP2(p[r]);
    }

    // ---- row sums: wave-local shuffle + cross-wave LDS
    #pragma unroll
    for (int r = 0; r < 8; ++r) {
        float s = p[r];
        #pragma unroll
        for (int off = 32; off; off >>= 1) s += __shfl_xor(s, off, 64);
        if (lane == 0) reds[r][w] = s;
    }
    __syncthreads();
    #pragma unroll
    for (int r = 0; r < 8; ++r) {
        const f32x4 sa = *(const f32x4*)&reds[r][0];
        const f32x4 sb = *(const f32x4*)&reds[r][4];
        const float gsum = ((sa.x + sa.y) + (sa.z + sa.w)) +
                           ((sb.x + sb.y) + (sb.z + sb.w));
        ps[r][k] = p[r] * RCP(gsum);
    }
    __syncthreads();

    // ---- PV: wave = (kq 0..3, dh 0..1); lane owns f32x2 of d
    const int kq   = w >> 1;
    const int dh   = w & 1;
    const int dcol = dh * 128 + 2 * lane;
    f32x2 a[QT];
    #pragma unroll
    for (int r = 0; r < QT; ++r) a[r] = (f32x2){0.f, 0.f};

    const float* __restrict__ vb = value + ((size_t)b * NK + kq * 128) * ND + dcol;
    for (int kk = 0; kk < 128; kk += 4) {
        const int kbase = kq * 128 + kk;
        const f32x2 v0 = *(const f32x2*)&vb[(size_t)(kk + 0) * ND];
        const f32x2 v1 = *(const f32x2*)&vb[(size_t)(kk + 1) * ND];
        const f32x2 v2 = *(const f32x2*)&vb[(size_t)(kk + 2) * ND];
        const f32x2 v3 = *(const f32x2*)&vb[(size_t)(kk + 3) * ND];
        #pragma unroll
        for (int half = 0; half < 2; ++half) {
            #pragma unroll
            for (int rr = 0; rr < 4; ++rr) {
                const int r = half * 4 + rr;
                const f32x4 P = *(const f32x4*)&ps[r][kbase];   // uniform b128
                a[r] = fma2(sp2(P.x), v0, a[r]);
                a[r] = fma2(sp2(P.y), v1, a[r]);
                a[r] = fma2(sp2(P.z), v2, a[r]);
                a[r] = fma2(sp2(P.w), v3, a[r]);
            }
        }
    }

    // ---- cross-wave reduce in two half-rounds (pacc = 12 KB)
    if (kq > 0) {
        #pragma unroll
        for (int r = 0; r < 4; ++r)
            *(f32x2*)&pacc[kq - 1][r][dcol] = a[r];
    }
    __syncthreads();
    if (kq == 0) {
        #pragma unroll
        for (int r = 0; r < 4; ++r) {
            f32x2 v = a[r];
            v += *(const f32x2*)&pacc[0][r][dcol];
            v += *(const f32x2*)&pacc[1][r][dcol];
            v += *(const f32x2*)&pacc[2][r][dcol];
            *(f32x2*)&out[(size_t)(b * NQ + q0 + r) * ND + dcol] = v;
        }
    }
    __syncthreads();
    if (kq > 0) {
        #pragma unroll
        for (int r = 0; r < 4; ++r)
            *(f32x2*)&pacc[kq - 1][r][dcol] = a[4 + r];
    }
    __syncthreads();
    if (kq == 0) {
        #pragma unroll
        for (int r = 0; r < 4; ++r) {
            f32x2 v = a[4 + r];
            v += *(const f32x2*)&pacc[0][r][dcol];
            v += *(const f32x2*)&pacc[1][r][dcol];
            v += *(const f32x2*)&pacc[2][r][dcol];
            *(f32x2*)&out[(size_t)(b * NQ + q0 + 4 + r) * ND + dcol] = v;
        }
    }
}

extern "C" void kernel_launch(void* const* d_in, const int* in_sizes, int n_in,
                              void* d_out, int out_size, void* d_ws, size_t ws_size,
                              hipStream_t stream) {
    const float* key   = (const float*)d_in[0];
    const float* query = (const float*)d_in[1];
    const float* value = (const float*)d_in[2];
    const unsigned char* mask = (const unsigned char*)d_in[3];
    const float* Wk  = (const float*)d_in[4];
    const float* Wq  = (const float*)d_in[5];
    const float* w_v = (const float*)d_in[6];
    float* out = (float*)d_out;

    float* Eq  = (float*)d_ws;                 // [NB*NQ, NH]
    float* Ekp = Eq + (size_t)NB * NQ * NH;    // [NB, NH, NK]

    proj_kernel<<<1024, 256, 0, stream>>>(query, key, Wq, Wk, Eq, Ekp);
    attn_kernel<<<NB * (NQ / QT), 512, 0, stream>>>(Eq, Ekp, value, mask, w_v, out);
}

// Round 10
// 48.250 us; speedup vs baseline: 2.4563x; 1.0071x over previous
//
#include <hip/hip_runtime.h>
#include <math.h>

#define NB 8
#define NQ 512
#define NK 512
#define NH 64
#define ND 256
#define QT 8     // q rows per attn block

typedef float f32x2 __attribute__((ext_vector_type(2)));
typedef float f32x4 __attribute__((ext_vector_type(4)));

#define EXP2(x) __builtin_amdgcn_exp2f(x)
#define RCP(x)  __builtin_amdgcn_rcpf(x)
#define SCALE2 2.8853900817779268f   // 2*log2(e) folded into projections
#define LOG2E  1.4426950408889634f

static __device__ __forceinline__ f32x2 sp2(float v) { return (f32x2){v, v}; }
static __device__ __forceinline__ f32x2 fma2(f32x2 a, f32x2 b, f32x2 c) {
    return __builtin_elementwise_fma(a, b, c);
}
static __device__ __forceinline__ f32x2 mk2(float x, float y) {
    return (f32x2){x, y};
}

// 4-way-rcp additive-attention partial: acc += N4/D4 over a 4-h group,
// packed over 2 adjacent k. eq/fq/w01 are wave-uniform scalars (SGPRs).
static __device__ __forceinline__ void score4(
    const f32x2 k0, const f32x2 k1, const f32x2 k2, const f32x2 k3,
    const f32x4 eqv, const f32x4 fqv, const float w01a, const float w01b,
    f32x2& acc)
{
    const f32x2 t0 = k0 * eqv.x;
    const f32x2 t1 = k1 * eqv.y;
    const f32x2 ua = t0 + t1 + 1.0f;
    const f32x2 da = fma2(t0, t1, ua);
    f32x2 na = fma2(k0, sp2(fqv.x), sp2(w01a));
    na = fma2(k1, sp2(fqv.y), na);
    const f32x2 t2 = k2 * eqv.z;
    const f32x2 t3 = k3 * eqv.w;
    const f32x2 ub = t2 + t3 + 1.0f;
    const f32x2 db = fma2(t2, t3, ub);
    f32x2 nb = fma2(k2, sp2(fqv.z), sp2(w01b));
    nb = fma2(k3, sp2(fqv.w), nb);
    const f32x2 D = da * db;
    f32x2 N = na * db;
    N = fma2(nb, da, N);
    const f32x2 rD = mk2(RCP(D.x), RCP(D.y));
    acc = fma2(N, rD, acc);
}

// ---------------- projection + exp2:
//  q rows -> qside[row][hc][{eq0..3, fq0..3}]  (fq = w_v[h^1]*eq), 32B units
//  k rows -> Ekp[b][h][k] (transposed)
// block 0 also emits w01g[32] (pairwise w sums) and wsumg (sum of w_v).
__global__ __launch_bounds__(256, 4) void proj_kernel(
    const float* __restrict__ query, const float* __restrict__ key,
    const float* __restrict__ Wq, const float* __restrict__ Wk,
    const float* __restrict__ w_v,
    float* __restrict__ qside, float* __restrict__ Ekp,
    float* __restrict__ w01g, float* __restrict__ wsumg)
{
    __shared__ __align__(16) float insT[ND][12];   // 12 KB
    __shared__ float pacc[3][4][NH][2];            // 6 KB wave partials
    const int t = threadIdx.x;
    const bool isK = blockIdx.x >= 512;
    const float* __restrict__ in = isK ? key : query;
    const float* __restrict__ W  = isK ? Wk : Wq;
    const int rowbase = (blockIdx.x & 511) * 8;

    {   // stage 8 rows x 256 d, transposed
        const int r = t & 7, c = (t >> 3) * 8;
        const float* src = in + (size_t)(rowbase + r) * ND + c;
        const f32x4 v0 = *(const f32x4*)src;
        const f32x4 v1 = *(const f32x4*)(src + 4);
        insT[c + 0][r] = v0.x; insT[c + 1][r] = v0.y;
        insT[c + 2][r] = v0.z; insT[c + 3][r] = v0.w;
        insT[c + 4][r] = v1.x; insT[c + 5][r] = v1.y;
        insT[c + 6][r] = v1.z; insT[c + 7][r] = v1.w;
    }
    __syncthreads();

    const int lane = t & 63;          // lane = h
    const int w    = t >> 6;          // wave = d-quarter
    const int d0   = w * 64;

    f32x2 acc[4] = {{0.f,0.f},{0.f,0.f},{0.f,0.f},{0.f,0.f}};
    for (int dd = 0; dd < 64; ++dd) {
        const int d = d0 + dd;
        const float wv = W[(size_t)d * NH + lane];         // coalesced L2
        const f32x4 rA = *(const f32x4*)&insT[d][0];       // uniform b128
        const f32x4 rB = *(const f32x4*)&insT[d][4];
        acc[0] = fma2(mk2(rA.x, rA.y), sp2(wv), acc[0]);
        acc[1] = fma2(mk2(rA.z, rA.w), sp2(wv), acc[1]);
        acc[2] = fma2(mk2(rB.x, rB.y), sp2(wv), acc[2]);
        acc[3] = fma2(mk2(rB.z, rB.w), sp2(wv), acc[3]);
    }
    if (w > 0) {
        #pragma unroll
        for (int rp = 0; rp < 4; ++rp)
            *(f32x2*)&pacc[w - 1][rp][lane][0] = acc[rp];
    }
    __syncthreads();
    if (w == 0) {
        float e[8];
        #pragma unroll
        for (int rp = 0; rp < 4; ++rp) {
            f32x2 a = acc[rp];
            a += *(const f32x2*)&pacc[0][rp][lane][0];
            a += *(const f32x2*)&pacc[1][rp][lane][0];
            a += *(const f32x2*)&pacc[2][rp][lane][0];
            e[2 * rp] = a.x; e[2 * rp + 1] = a.y;
        }
        #pragma unroll
        for (int j = 0; j < 8; ++j) {
            const float x = fminf(fmaxf(e[j] * SCALE2, -30.f), 30.f);
            e[j] = EXP2(x);
        }
        if (!isK) {
            const float wx = w_v[lane ^ 1];
            #pragma unroll
            for (int j = 0; j < 8; ++j) {
                const int g = rowbase + j;
                float* dst = qside + ((size_t)g * 16 + (lane >> 2)) * 8 + (lane & 3);
                dst[0] = e[j];
                dst[4] = wx * e[j];
            }
        } else {
            #pragma unroll
            for (int j = 0; j < 8; ++j) {
                const int g = rowbase + j;
                const int bb = g >> 9, kk = g & 511;
                Ekp[((size_t)bb * NH + lane) * NK + kk] = e[j];
            }
        }
    }
    if (blockIdx.x == 0) {
        if (t < 32) w01g[t] = w_v[2 * t] + w_v[2 * t + 1];
        if (t == 64) {
            float s = 0.f;
            for (int h = 0; h < NH; ++h) s += w_v[h];
            wsumg[0] = s;
        }
    }
}

// ---------------- fused score + softmax + PV
// grid = 512 blocks (XCD-swizzled), 512 threads (8 waves).
// Score: thread = 2 adjacent k (f32x2) x 4 rows; wave w: k-quarter (w&3),
// row-half (w>>2). q-side read via uniform s_loads (qside). No score LDS.
__global__ __launch_bounds__(512, 4) void attn_kernel(
    const float* __restrict__ qside, const float* __restrict__ Ekp,
    const float* __restrict__ value, const unsigned char* __restrict__ mask,
    const float* __restrict__ w01g, const float* __restrict__ wsumg,
    float* __restrict__ out)
{
    __shared__ __align__(16) float ps[QT][NK];     // 16 KB pre-normalized probs
    __shared__ __align__(16) float reds[QT][4];    // wave row-sum partials
    __shared__ __align__(16) float pacc[3][4][ND]; // 12 KB PV partials

    const int t    = threadIdx.x;
    const int lane = t & 63;
    const int w    = t >> 6;
    // XCD-aware swizzle: XCD x gets blocks [64x, 64x+64) = exactly batch x's
    // Ek (256KB) + V (512KB) resident in its 4MB L2.
    const int bid  = ((int)(blockIdx.x & 7) << 6) | ((int)blockIdx.x >> 3);
    const int b    = bid >> 6;
    const int q0   = (bid & 63) * QT;
    const int rh   = __builtin_amdgcn_readfirstlane(t >> 8);  // row half 0/1
    const int kp   = t & 255;                                 // k-pair index

    const float wsumL = wsumg[0] * LOG2E;
    const float* __restrict__ qs  = qside + (size_t)(b * NQ + q0 + rh * 4) * 128;
    const float* __restrict__ ekc = Ekp + (size_t)b * NH * NK + 2 * kp;

    f32x2 eA[4], eB[4];
    #pragma unroll
    for (int j = 0; j < 4; ++j) eA[j] = *(const f32x2*)&ekc[(size_t)j * NK];
    #pragma unroll
    for (int j = 0; j < 4; ++j) eB[j] = *(const f32x2*)&ekc[(size_t)(4 + j) * NK];

    f32x2 acc[4] = {{0.f,0.f},{0.f,0.f},{0.f,0.f},{0.f,0.f}};

    for (int hc = 0; hc < 16; hc += 2) {
        {   // even chunk: consume eA, prefetch hc+2 into eA
            const f32x2 k0 = eA[0], k1 = eA[1], k2 = eA[2], k3 = eA[3];
            if (hc + 2 < 16) {
                #pragma unroll
                for (int j = 0; j < 4; ++j)
                    eA[j] = *(const f32x2*)&ekc[(size_t)(4 * (hc + 2) + j) * NK];
            }
            const float wa = w01g[2 * hc], wb = w01g[2 * hc + 1];
            #pragma unroll
            for (int r = 0; r < 4; ++r) {
                const f32x4 eqv = *(const f32x4*)&qs[r * 128 + hc * 8];     // s_load
                const f32x4 fqv = *(const f32x4*)&qs[r * 128 + hc * 8 + 4]; // s_load
                score4(k0, k1, k2, k3, eqv, fqv, wa, wb, acc[r]);
            }
        }
        {   // odd chunk: consume eB, prefetch hc+3 into eB
            const f32x2 k0 = eB[0], k1 = eB[1], k2 = eB[2], k3 = eB[3];
            if (hc + 3 < 16) {
                #pragma unroll
                for (int j = 0; j < 4; ++j)
                    eB[j] = *(const f32x2*)&ekc[(size_t)(4 * (hc + 3) + j) * NK];
            }
            const float wa = w01g[2 * hc + 2], wb = w01g[2 * hc + 3];
            #pragma unroll
            for (int r = 0; r < 4; ++r) {
                const f32x4 eqv = *(const f32x4*)&qs[r * 128 + (hc + 1) * 8];
                const f32x4 fqv = *(const f32x4*)&qs[r * 128 + (hc + 1) * 8 + 4];
                score4(k0, k1, k2, k3, eqv, fqv, wa, wb, acc[r]);
            }
        }
    }

    // ---- mask + exp (no max-subtraction: |score| <= sum|w_h| ~ 6.4)
    const unsigned char* __restrict__ mb =
        mask + (size_t)(b * NQ + q0 + rh * 4) * NK + 2 * kp;
    f32x2 p[4];
    #pragma unroll
    for (int r = 0; r < 4; ++r) {
        f32x2 arg = fma2(acc[r], sp2(-2.f * LOG2E), sp2(wsumL));
        const unsigned short m = *(const unsigned short*)(mb + (size_t)r * NK);
        if (m & 0x00ff) arg.x = -__builtin_inff();
        if (m & 0xff00) arg.y = -__builtin_inff();
        p[r] = mk2(EXP2(arg.x), EXP2(arg.y));
    }

    // ---- row sums: wave shuffle + cross-wave LDS (4 waves per row)
    #pragma unroll
    for (int r = 0; r < 4; ++r) {
        float s = p[r].x + p[r].y;
        #pragma unroll
        for (int off = 32; off; off >>= 1) s += __shfl_xor(s, off, 64);
        if (lane == 0) reds[rh * 4 + r][w & 3] = s;
    }
    __syncthreads();
    #pragma unroll
    for (int r = 0; r < 4; ++r) {
        const f32x4 sv = *(const f32x4*)&reds[rh * 4 + r][0];
        const float gsum = (sv.x + sv.y) + (sv.z + sv.w);
        p[r] = p[r] * RCP(gsum);
        *(f32x2*)&ps[rh * 4 + r][2 * kp] = p[r];
    }
    __syncthreads();

    // ---- PV: wave = (kq 0..3, dh 0..1); lane owns f32x2 of d
    const int kq   = w >> 1;
    const int dh   = w & 1;
    const int dcol = dh * 128 + 2 * lane;
    f32x2 a[QT];
    #pragma unroll
    for (int r = 0; r < QT; ++r) a[r] = (f32x2){0.f, 0.f};

    const float* __restrict__ vb = value + ((size_t)b * NK + kq * 128) * ND + dcol;
    for (int kk = 0; kk < 128; kk += 4) {
        const int kbase = kq * 128 + kk;
        const f32x2 v0 = *(const f32x2*)&vb[(size_t)(kk + 0) * ND];
        const f32x2 v1 = *(const f32x2*)&vb[(size_t)(kk + 1) * ND];
        const f32x2 v2 = *(const f32x2*)&vb[(size_t)(kk + 2) * ND];
        const f32x2 v3 = *(const f32x2*)&vb[(size_t)(kk + 3) * ND];
        #pragma unroll
        for (int half = 0; half < 2; ++half) {
            #pragma unroll
            for (int rr = 0; rr < 4; ++rr) {
                const int r = half * 4 + rr;
                const f32x4 P = *(const f32x4*)&ps[r][kbase];   // uniform b128
                a[r] = fma2(sp2(P.x), v0, a[r]);
                a[r] = fma2(sp2(P.y), v1, a[r]);
                a[r] = fma2(sp2(P.z), v2, a[r]);
                a[r] = fma2(sp2(P.w), v3, a[r]);
            }
        }
    }

    // ---- cross-wave reduce in two half-rounds (pacc = 12 KB)
    if (kq > 0) {
        #pragma unroll
        for (int r = 0; r < 4; ++r)
            *(f32x2*)&pacc[kq - 1][r][dcol] = a[r];
    }
    __syncthreads();
    if (kq == 0) {
        #pragma unroll
        for (int r = 0; r < 4; ++r) {
            f32x2 v = a[r];
            v += *(const f32x2*)&pacc[0][r][dcol];
            v += *(const f32x2*)&pacc[1][r][dcol];
            v += *(const f32x2*)&pacc[2][r][dcol];
            *(f32x2*)&out[(size_t)(b * NQ + q0 + r) * ND + dcol] = v;
        }
    }
    __syncthreads();
    if (kq > 0) {
        #pragma unroll
        for (int r = 0; r < 4; ++r)
            *(f32x2*)&pacc[kq - 1][r][dcol] = a[4 + r];
    }
    __syncthreads();
    if (kq == 0) {
        #pragma unroll
        for (int r = 0; r < 4; ++r) {
            f32x2 v = a[4 + r];
            v += *(const f32x2*)&pacc[0][r][dcol];
            v += *(const f32x2*)&pacc[1][r][dcol];
            v += *(const f32x2*)&pacc[2][r][dcol];
            *(f32x2*)&out[(size_t)(b * NQ + q0 + 4 + r) * ND + dcol] = v;
        }
    }
}

extern "C" void kernel_launch(void* const* d_in, const int* in_sizes, int n_in,
                              void* d_out, int out_size, void* d_ws, size_t ws_size,
                              hipStream_t stream) {
    const float* key   = (const float*)d_in[0];
    const float* query = (const float*)d_in[1];
    const float* value = (const float*)d_in[2];
    const unsigned char* mask = (const unsigned char*)d_in[3];
    const float* Wk  = (const float*)d_in[4];
    const float* Wq  = (const float*)d_in[5];
    const float* w_v = (const float*)d_in[6];
    float* out = (float*)d_out;

    float* Ekp   = (float*)d_ws;                        // [NB, NH, NK]   1 MB
    float* qside = Ekp + (size_t)NB * NH * NK;          // [NB*NQ, 128]   2 MB
    float* w01g  = qside + (size_t)NB * NQ * 128;       // [32]
    float* wsumg = w01g + 32;                           // [1]

    proj_kernel<<<1024, 256, 0, stream>>>(query, key, Wq, Wk, w_v,
                                          qside, Ekp, w01g, wsumg);
    attn_kernel<<<NB * (NQ / QT), 512, 0, stream>>>(qside, Ekp, value, mask,
                                                    w01g, wsumg, out);
}